// Round 1
// baseline (105.973 us; speedup 1.0000x reference)
//
#include <hip/hip_runtime.h>
#include <hip/hip_fp16.h>

typedef _Float16 f16;
typedef f16 f16x2 __attribute__((ext_vector_type(2)));
typedef f16 f16x8 __attribute__((ext_vector_type(8)));
typedef float f32x4 __attribute__((ext_vector_type(4)));

#define BB 32
#define NN 1024
#define HH 128

// workspace layout (bytes)
#define WT0_OFF   0         // f16 [128][1024]  : Wt0[h][j] = W0[9+j][h]
#define WT1_OFF   262144    // f16 [128][128]   : Wt1[ho][hi] = W1[hi][ho]
#define WT2_OFF   294912    // f16 [128][128]   : Wt2[o][h]   = W2[h][o]
#define W8_OFF    327680    // f32 [128]        : W0[8][:]  (norm row)
#define BIAS0_OFF 328192    // f32 [32][128]    : b0 + u[b] @ W0[0:8,:]

__global__ __launch_bounds__(256) void prep_kernel(
    const float* __restrict__ u,  const float* __restrict__ W0,
    const float* __restrict__ b0, const float* __restrict__ W1,
    const float* __restrict__ W2,
    f16* __restrict__ Wt0, f16* __restrict__ Wt1, f16* __restrict__ Wt2,
    float* __restrict__ w8v, float* __restrict__ bias0)
{
    __shared__ __align__(16) f16 T[128 * 130];
    const int t = threadIdx.x;
    const int blk = blockIdx.x;
    if (blk < 16) {
        // transpose 64 j-rows of the dots part of W0 into Wt0[h][j]
        const int j0 = blk * 64;
        for (int k = 0; k < 32; ++k) {
            int flat = k * 256 + t;
            int j = flat >> 7, h = flat & 127;
            T[j * 130 + h] = (f16)W0[(9 + j0 + j) * 128 + h];
        }
        __syncthreads();
        for (int k = 0; k < 32; ++k) {
            int flat = k * 256 + t;
            int h = flat >> 6, jj = flat & 63;
            Wt0[h * 1024 + j0 + jj] = T[jj * 130 + h];
        }
    } else if (blk < 18) {
        const float* Ws = (blk == 16) ? W1 : W2;
        f16* Wd = (blk == 16) ? Wt1 : Wt2;
        for (int k = 0; k < 64; ++k) {
            int flat = k * 256 + t;
            int hi = flat >> 7, ho = flat & 127;
            T[ho * 130 + hi] = (f16)Ws[hi * 128 + ho];
        }
        __syncthreads();
        for (int k = 0; k < 64; ++k) {
            int flat = k * 256 + t;
            int ho = flat >> 7, hi = flat & 127;
            Wd[ho * 128 + hi] = T[ho * 130 + hi];
        }
    } else {
        if (t < 128) w8v[t] = W0[8 * 128 + t];
        for (int k = 0; k < 16; ++k) {
            int flat = k * 256 + t;
            int b = flat >> 7, h = flat & 127;
            float s = b0[h];
#pragma unroll
            for (int g = 0; g < 8; ++g) s += u[b * 8 + g] * W0[g * 128 + h];
            bias0[b * 128 + h] = s;
        }
    }
}

// Fused: per (batch, 64-row i-tile): layer0 (dots generated on the fly),
// layer1, layer2, and the fk.x contraction epilogue.
__global__ __launch_bounds__(256, 2) void fused_kernel(
    const float* __restrict__ x,   const float* __restrict__ b1p,
    const float* __restrict__ b2p,
    const f16* __restrict__ Wt0, const f16* __restrict__ Wt1,
    const f16* __restrict__ Wt2, const float* __restrict__ w8v,
    const float* __restrict__ bias0, float* __restrict__ outp)
{
    // LDS: 74 KB total -> 2 blocks/CU
    __shared__ __align__(16) f16 Dsh[64 * 136];    // D tile / h1 tile (A-layout, +8 pad)
    __shared__ __align__(16) f16 Wsh[128 * 136];   // current B tile [n][k]
    __shared__ __align__(16) f16 H0sh[64 * 136];   // h0 tile (A-layout)
    __shared__ __align__(16) float xi[64 * 4];
    __shared__ __align__(16) float xj[128 * 4];
    __shared__ float normv[64];
    __shared__ float biass[128];
    __shared__ float w8s[128];

    const int t = threadIdx.x;
    const int bid = blockIdx.x;
    const int b = bid >> 4;
    const int i0 = (bid & 15) * 64;

    // stage x_i tile + per-batch bias
    if (t < 192) {
        int i = t / 3, d = t - i * 3;
        xi[i * 4 + d] = x[((size_t)(b * NN + i0 + i)) * 3 + d];
    }
    if (t < 128) { biass[t] = bias0[b * 128 + t]; w8s[t] = w8v[t]; }
    __syncthreads();
    if (t < 64) {
        float a0 = xi[t * 4], a1 = xi[t * 4 + 1], a2 = xi[t * 4 + 2];
        normv[t] = __builtin_amdgcn_sqrtf(a0 * a0 + a1 * a1 + a2 * a2);
        xi[t * 4 + 3] = 0.f;
    }

    const int lane = t & 63, wv = t >> 6;
    const int wm = wv >> 1, wn = wv & 1;   // wave tile: 32 rows x 64 cols
    const int lm = lane & 15, q = lane >> 4;

    f32x4 acc[2][4];
#pragma unroll
    for (int mt = 0; mt < 2; ++mt)
#pragma unroll
        for (int nt = 0; nt < 4; ++nt)
#pragma unroll
            for (int e = 0; e < 4; ++e) acc[mt][nt][e] = 0.f;

    auto zero_acc = [&]() {
#pragma unroll
        for (int mt = 0; mt < 2; ++mt)
#pragma unroll
            for (int nt = 0; nt < 4; ++nt)
#pragma unroll
                for (int e = 0; e < 4; ++e) acc[mt][nt][e] = 0.f;
    };

    auto mfma_block = [&](const f16* Ab) {
#pragma unroll
        for (int ks = 0; ks < 4; ++ks) {
            const int ko = ks * 32 + q * 8;
            f16x8 af[2], bf[4];
#pragma unroll
            for (int mt = 0; mt < 2; ++mt)
                af[mt] = *(const f16x8*)(Ab + (wm * 32 + mt * 16 + lm) * 136 + ko);
#pragma unroll
            for (int nt = 0; nt < 4; ++nt)
                bf[nt] = *(const f16x8*)(Wsh + (wn * 64 + nt * 16 + lm) * 136 + ko);
#pragma unroll
            for (int mt = 0; mt < 2; ++mt)
#pragma unroll
                for (int nt = 0; nt < 4; ++nt)
                    acc[mt][nt] = __builtin_amdgcn_mfma_f32_16x16x32_f16(
                        af[mt], bf[nt], acc[mt][nt], 0, 0, 0);
        }
    };

    const int di = t >> 2;       // D row 0..63
    const int g4 = t & 3;        // 32-wide j segment

    // ---- layer 0: K-loop over 8 chunks of 128 dots ----
    for (int jc = 0; jc < 8; ++jc) {
        // stage x_j rows for this chunk
        for (int idx = t; idx < 384; idx += 256) {
            int j = idx / 3, d = idx - j * 3;
            xj[j * 4 + d] = x[((size_t)(b * NN + jc * 128 + j)) * 3 + d];
        }
        // stage W0^T chunk [128 h][128 k]
        {
            const int row = t >> 4, c8 = (t & 15) * 8;
#pragma unroll
            for (int r = 0; r < 8; ++r) {
                int rr = row + r * 16;
                *(uint4*)&Wsh[rr * 136 + c8] =
                    *(const uint4*)&Wt0[rr * 1024 + jc * 128 + c8];
            }
        }
        __syncthreads();
        // generate D tile: 64 x 128 entries, 32 per thread
        {
            const float4 xiv = *(const float4*)&xi[di * 4];
#pragma unroll
            for (int tt = 0; tt < 16; ++tt) {
                int jo = ((tt + g4) & 15) * 2;      // rotate to spread LDS banks
                int j = g4 * 32 + jo;
                float4 a = *(const float4*)&xj[j * 4];
                float4 c = *(const float4*)&xj[j * 4 + 4];
                float d0 = __builtin_amdgcn_sqrtf(
                    fmaf(xiv.x, a.x, fmaf(xiv.y, a.y, xiv.z * a.z)));
                float d1 = __builtin_amdgcn_sqrtf(
                    fmaf(xiv.x, c.x, fmaf(xiv.y, c.y, xiv.z * c.z)));
                f16x2 p; p.x = (f16)d0; p.y = (f16)d1;
                *(f16x2*)&Dsh[di * 136 + j] = p;
            }
        }
        __syncthreads();
        mfma_block(Dsh);
        __syncthreads();
    }

    // epilogue0: h0 = leaky(acc + bias_b[h] + norm_i*W0[8,h]) -> H0sh ; stage Wt1
#pragma unroll
    for (int mt = 0; mt < 2; ++mt)
#pragma unroll
        for (int nt = 0; nt < 4; ++nt) {
            const int h = wn * 64 + nt * 16 + lm;
            const float bh = biass[h], w8h = w8s[h];
            f32x4 v = acc[mt][nt];
#pragma unroll
            for (int r = 0; r < 4; ++r) {
                int i = wm * 32 + mt * 16 + q * 4 + r;
                float val = v[r] + bh + normv[i] * w8h;
                val = val > 0.f ? val : 0.01f * val;
                H0sh[i * 136 + h] = (f16)val;
            }
        }
    {
        const int row = t >> 4, c8 = (t & 15) * 8;
#pragma unroll
        for (int r = 0; r < 8; ++r) {
            int rr = row + r * 16;
            *(uint4*)&Wsh[rr * 136 + c8] = *(const uint4*)&Wt1[rr * 128 + c8];
        }
    }
    __syncthreads();

    // ---- layer 1 ----
    zero_acc();
    mfma_block(H0sh);
    __syncthreads();
    // epilogue1: h1 = leaky(acc + b1) -> Dsh ; stage Wt2
#pragma unroll
    for (int mt = 0; mt < 2; ++mt)
#pragma unroll
        for (int nt = 0; nt < 4; ++nt) {
            const int h = wn * 64 + nt * 16 + lm;
            const float bh = b1p[h];
            f32x4 v = acc[mt][nt];
#pragma unroll
            for (int r = 0; r < 4; ++r) {
                int i = wm * 32 + mt * 16 + q * 4 + r;
                float val = v[r] + bh;
                val = val > 0.f ? val : 0.01f * val;
                Dsh[i * 136 + h] = (f16)val;
            }
        }
    {
        const int row = t >> 4, c8 = (t & 15) * 8;
#pragma unroll
        for (int r = 0; r < 8; ++r) {
            int rr = row + r * 16;
            *(uint4*)&Wsh[rr * 136 + c8] = *(const uint4*)&Wt2[rr * 128 + c8];
        }
    }
    __syncthreads();

    // ---- layer 2 ----
    zero_acc();
    mfma_block(Dsh);

    // contraction epilogue: out[b,o,d] += sum_i (acc[i,o]+b2[o]) * x[i,d] / N
    float p[4][3];
#pragma unroll
    for (int nt = 0; nt < 4; ++nt)
#pragma unroll
        for (int d = 0; d < 3; ++d) p[nt][d] = 0.f;
    float bo[4];
#pragma unroll
    for (int nt = 0; nt < 4; ++nt) bo[nt] = b2p[wn * 64 + nt * 16 + lm];
#pragma unroll
    for (int mt = 0; mt < 2; ++mt)
#pragma unroll
        for (int r = 0; r < 4; ++r) {
            int i = wm * 32 + mt * 16 + q * 4 + r;
            float x0 = xi[i * 4], x1 = xi[i * 4 + 1], x2 = xi[i * 4 + 2];
#pragma unroll
            for (int nt = 0; nt < 4; ++nt) {
                float fkv = acc[mt][nt][r] + bo[nt];
                p[nt][0] = fmaf(fkv, x0, p[nt][0]);
                p[nt][1] = fmaf(fkv, x1, p[nt][1]);
                p[nt][2] = fmaf(fkv, x2, p[nt][2]);
            }
        }
#pragma unroll
    for (int nt = 0; nt < 4; ++nt)
#pragma unroll
        for (int d = 0; d < 3; ++d) {
            float s = p[nt][d];
            s += __shfl_xor(s, 16);
            s += __shfl_xor(s, 32);
            if (q == 0) {
                int o = wn * 64 + nt * 16 + lm;
                atomicAdd(&outp[(b * 128 + o) * 3 + d], s * (1.0f / 1024.0f));
            }
        }
}

extern "C" void kernel_launch(void* const* d_in, const int* in_sizes, int n_in,
                              void* d_out, int out_size, void* d_ws, size_t ws_size,
                              hipStream_t stream) {
    const float* x  = (const float*)d_in[0];
    const float* u  = (const float*)d_in[1];
    const float* W0 = (const float*)d_in[2];
    const float* b0 = (const float*)d_in[3];
    const float* W1 = (const float*)d_in[4];
    const float* b1 = (const float*)d_in[5];
    const float* W2 = (const float*)d_in[6];
    const float* b2 = (const float*)d_in[7];

    char* ws = (char*)d_ws;
    f16*   Wt0   = (f16*)(ws + WT0_OFF);
    f16*   Wt1   = (f16*)(ws + WT1_OFF);
    f16*   Wt2   = (f16*)(ws + WT2_OFF);
    float* w8v   = (float*)(ws + W8_OFF);
    float* bias0 = (float*)(ws + BIAS0_OFF);
    float* out   = (float*)d_out;

    hipMemsetAsync(d_out, 0, (size_t)out_size * sizeof(float), stream);
    prep_kernel<<<19, 256, 0, stream>>>(u, W0, b0, W1, W2, Wt0, Wt1, Wt2, w8v, bias0);
    fused_kernel<<<512, 256, 0, stream>>>(x, b1, b2, Wt0, Wt1, Wt2, w8v, bias0, out);
}

// Round 2
// 100.440 us; speedup vs baseline: 1.0551x; 1.0551x over previous
//
#include <hip/hip_runtime.h>
#include <hip/hip_fp16.h>

typedef _Float16 f16;
typedef f16 f16x4 __attribute__((ext_vector_type(4)));
typedef f16 f16x8 __attribute__((ext_vector_type(8)));
typedef float f32x4 __attribute__((ext_vector_type(4)));

#define NN 1024

// workspace layout (bytes)
#define WT0_OFF   0         // f16 [128][1024]  : Wt0[h][j] = W0[9+j][h]
#define WT1_OFF   262144    // f16 [128][128]   : Wt1[ho][hi] = W1[hi][ho]
#define WT2_OFF   294912    // f16 [128][128]   : Wt2[o][h]   = W2[h][o]
#define W8_OFF    327680    // f32 [128]        : W0[8][:]  (norm row)
#define BIAS0_OFF 328192    // f32 [32][128]    : b0 + u[b] @ W0[0:8,:]

__global__ __launch_bounds__(256) void prep_kernel(
    const float* __restrict__ u,  const float* __restrict__ W0,
    const float* __restrict__ b0, const float* __restrict__ W1,
    const float* __restrict__ W2,
    f16* __restrict__ Wt0, f16* __restrict__ Wt1, f16* __restrict__ Wt2,
    float* __restrict__ w8v, float* __restrict__ bias0)
{
    __shared__ __align__(16) f16 T[128 * 130];
    const int t = threadIdx.x;
    const int blk = blockIdx.x;
    if (blk < 16) {
        const int j0 = blk * 64;
        for (int k = 0; k < 32; ++k) {
            int flat = k * 256 + t;
            int j = flat >> 7, h = flat & 127;
            T[j * 130 + h] = (f16)W0[(9 + j0 + j) * 128 + h];
        }
        __syncthreads();
        for (int k = 0; k < 32; ++k) {
            int flat = k * 256 + t;
            int h = flat >> 6, jj = flat & 63;
            Wt0[h * 1024 + j0 + jj] = T[jj * 130 + h];
        }
    } else if (blk < 18) {
        const float* Ws = (blk == 16) ? W1 : W2;
        f16* Wd = (blk == 16) ? Wt1 : Wt2;
        for (int k = 0; k < 64; ++k) {
            int flat = k * 256 + t;
            int hi = flat >> 7, ho = flat & 127;
            T[ho * 130 + hi] = (f16)Ws[hi * 128 + ho];
        }
        __syncthreads();
        for (int k = 0; k < 64; ++k) {
            int flat = k * 256 + t;
            int ho = flat >> 7, hi = flat & 127;
            Wd[ho * 128 + hi] = T[ho * 130 + hi];
        }
    } else {
        if (t < 128) w8v[t] = W0[8 * 128 + t];
        for (int k = 0; k < 16; ++k) {
            int flat = k * 256 + t;
            int b = flat >> 7, h = flat & 127;
            float s = b0[h];
#pragma unroll
            for (int g = 0; g < 8; ++g) s += u[b * 8 + g] * W0[g * 128 + h];
            bias0[b * 128 + h] = s;
        }
    }
}

// Fused kernel: per (batch, 64-row i-tile). Single-barrier software-pipelined
// K-loop (16 chunks of 64 j): dots via small MFMA, swizzled double-buffered LDS.
__global__ __launch_bounds__(256, 2) void fused_kernel(
    const float* __restrict__ x,   const float* __restrict__ b1p,
    const float* __restrict__ b2p,
    const f16* __restrict__ Wt0, const f16* __restrict__ Wt1,
    const f16* __restrict__ Wt2, const float* __restrict__ w8v,
    const float* __restrict__ bias0, float* __restrict__ outp)
{
    // XOR-swizzled tiles: element (row, col) of a 64-wide tile lives at
    // row*64 + ((col&~7) ^ ((row&7)<<3)) + (col&7). b128/b64 accesses stay
    // within one 8-f16 swizzle unit -> conflict-free reads.
    __shared__ __align__(16) f16 Dsh[2][64 * 64];   // 16 KB: D / h0 / h1 (A-operand)
    __shared__ __align__(16) f16 Wsh[2][128 * 64];  // 32 KB: B-operand K-chunks
    __shared__ __align__(16) float xi[64 * 4];
    __shared__ float normv[64];
    __shared__ float biass[128];
    __shared__ float w8s[128];

    const int t = threadIdx.x;
    const int b = blockIdx.x >> 4;
    const int i0 = (blockIdx.x & 15) * 64;

    if (t < 192) {
        int i = t / 3, d = t - i * 3;
        xi[i * 4 + d] = x[(size_t)(b * NN + i0 + i) * 3 + d];
    }
    if (t < 128) { biass[t] = bias0[b * 128 + t]; w8s[t] = w8v[t]; }
    __syncthreads();
    if (t < 64) {
        float a0 = xi[t * 4], a1 = xi[t * 4 + 1], a2 = xi[t * 4 + 2];
        normv[t] = __builtin_amdgcn_sqrtf(a0 * a0 + a1 * a1 + a2 * a2);
        xi[t * 4 + 3] = 0.f;
    }
    __syncthreads();

    const int lane = t & 63, wv = t >> 6;
    const int wm = wv >> 1, wn = wv & 1;     // main-mfma wave tile: 32 i x 64 h
    const int lm = lane & 15, q = lane >> 4;

    // xi B-fragments for the dot-MFMA (fixed per block): lane(q==0,lm) holds
    // coords of i = it*16+lm in k-slots 0..2; other q-lanes zero.
    f16x4 bi[4];
#pragma unroll
    for (int it = 0; it < 4; ++it) {
        f16x4 v; v[0] = (f16)0; v[1] = (f16)0; v[2] = (f16)0; v[3] = (f16)0;
        if (q == 0) {
            int ii = it * 16 + lm;
            v[0] = (f16)xi[ii * 4];
            v[1] = (f16)xi[ii * 4 + 1];
            v[2] = (f16)xi[ii * 4 + 2];
        }
        bi[it] = v;
    }

    f32x4 acc[2][4];
    auto zero_acc = [&]() {
#pragma unroll
        for (int mt = 0; mt < 2; ++mt)
#pragma unroll
            for (int nt = 0; nt < 4; ++nt)
#pragma unroll
                for (int e = 0; e < 4; ++e) acc[mt][nt][e] = 0.f;
    };
    zero_acc();

    // load xj A-fragment for dot-MFMA of chunk jc (global f32 -> f16)
    auto load_aj = [&](int jc) -> f16x4 {
        f16x4 a; a[0] = (f16)0; a[1] = (f16)0; a[2] = (f16)0; a[3] = (f16)0;
        if (q == 0) {
            const float* p = x + (size_t)(b * NN + jc * 64 + wv * 16 + lm) * 3;
            a[0] = (f16)p[0]; a[1] = (f16)p[1]; a[2] = (f16)p[2];
        }
        return a;
    };

    // dot-MFMA chunk -> sqrt -> packed b64 stores into Dsh[buf]
    auto dotstore = [&](f16x4 aj, int buf) {
        f32x4 cg[4];
#pragma unroll
        for (int it = 0; it < 4; ++it) {
            f32x4 z; z[0] = 0.f; z[1] = 0.f; z[2] = 0.f; z[3] = 0.f;
            cg[it] = __builtin_amdgcn_mfma_f32_16x16x16f16(aj, bi[it], z, 0, 0, 0);
        }
#pragma unroll
        for (int it = 0; it < 4; ++it) {
            f16x4 dv;
#pragma unroll
            for (int r = 0; r < 4; ++r)
                dv[r] = (f16)__builtin_amdgcn_sqrtf(fmaxf(cg[it][r], 0.f));
            // lane holds D[j = wv*16 + q*4 + r][i = it*16 + lm]
            int row = it * 16 + lm;            // i (A-operand row)
            int colstart = wv * 16 + q * 4;    // j (k-dim), 4 contiguous
            int addr = row * 64 + (((colstart & ~7) ^ ((row & 7) << 3)) | (colstart & 7));
            *(f16x4*)&Dsh[buf][addr] = dv;
        }
    };

    // main MFMA over one 64-wide K-chunk
    auto mfma2 = [&](const f16* Ab, const f16* Bb) {
#pragma unroll
        for (int ks = 0; ks < 2; ++ks) {
            const int col = ks * 32 + q * 8;
            f16x8 af[2], bf[4];
#pragma unroll
            for (int mt = 0; mt < 2; ++mt) {
                int row = wm * 32 + mt * 16 + lm;
                af[mt] = *(const f16x8*)(Ab + row * 64 + (col ^ ((row & 7) << 3)));
            }
#pragma unroll
            for (int nt = 0; nt < 4; ++nt) {
                int row = wn * 64 + nt * 16 + lm;
                bf[nt] = *(const f16x8*)(Bb + row * 64 + (col ^ ((row & 7) << 3)));
            }
#pragma unroll
            for (int mt = 0; mt < 2; ++mt)
#pragma unroll
                for (int nt = 0; nt < 4; ++nt)
                    acc[mt][nt] = __builtin_amdgcn_mfma_f32_16x16x32_f16(
                        af[mt], bf[nt], acc[mt][nt], 0, 0, 0);
        }
    };

    // stage a [128][64] B chunk into Wsh[buf] via registers (swizzled)
    auto stageW = [&](const f16* src, int stride, int srcCol, int buf) {
#pragma unroll
        for (int k = 0; k < 4; ++k) {
            int uu = t + k * 256;
            int row = uu >> 3, unit = uu & 7;
            uint4 v = *(const uint4*)(src + row * stride + srcCol + unit * 8);
            int addr = row * 64 + ((unit * 8) ^ ((row & 7) << 3));
            *(uint4*)&Wsh[buf][addr] = v;
        }
    };

    // ---- prologue: chunk 0 ----
    dotstore(load_aj(0), 0);
    stageW(Wt0, 1024, 0, 0);
    __syncthreads();

    // ---- pipelined layer-0 K-loop: ONE barrier per chunk ----
    int cur = 0;
    for (int jc = 0; jc < 16; ++jc) {
        const int nxt = cur ^ 1;
        // issue next chunk's global W loads first (latency hiding)
        const f16* wsrc = (jc < 15) ? Wt0 : Wt1;
        const int wstride = (jc < 15) ? 1024 : 128;
        const int wcol = (jc < 15) ? (jc + 1) * 64 : 0;
        uint4 wreg[4];
#pragma unroll
        for (int k = 0; k < 4; ++k) {
            int uu = t + k * 256;
            int row = uu >> 3, unit = uu & 7;
            wreg[k] = *(const uint4*)(wsrc + row * wstride + wcol + unit * 8);
        }
        if (jc < 15) dotstore(load_aj(jc + 1), nxt);
#pragma unroll
        for (int k = 0; k < 4; ++k) {
            int uu = t + k * 256;
            int row = uu >> 3, unit = uu & 7;
            int addr = row * 64 + ((unit * 8) ^ ((row & 7) << 3));
            *(uint4*)&Wsh[nxt][addr] = wreg[k];
        }
        mfma2(Dsh[cur], Wsh[cur]);
        __syncthreads();
        cur = nxt;
    }
    // after loop: Wsh[0] = Wt1 k-chunk 0

    // ---- epilogue 0: h0 = leaky(acc + bias + norm*w8) -> Dsh[0/1] (h halves) ----
#pragma unroll
    for (int mt = 0; mt < 2; ++mt)
#pragma unroll
        for (int nt = 0; nt < 4; ++nt) {
            const int h = wn * 64 + nt * 16 + lm;
            const float bh = biass[h], w8h = w8s[h];
            const int hh = h & 63;
#pragma unroll
            for (int r = 0; r < 4; ++r) {
                int i = wm * 32 + mt * 16 + q * 4 + r;
                float val = acc[mt][nt][r] + bh + normv[i] * w8h;
                val = val > 0.f ? val : 0.01f * val;
                int addr = i * 64 + (((hh & ~7) ^ ((i & 7) << 3)) | (hh & 7));
                Dsh[wn][addr] = (f16)val;
            }
        }
    stageW(Wt1, 128, 64, 1);
    __syncthreads();

    // ---- layer 1 ----
    zero_acc();
    mfma2(Dsh[0], Wsh[0]);
    mfma2(Dsh[1], Wsh[1]);
    __syncthreads();

    // ---- epilogue 1: h1 = leaky(acc + b1) -> Dsh ; stage Wt2 ----
#pragma unroll
    for (int mt = 0; mt < 2; ++mt)
#pragma unroll
        for (int nt = 0; nt < 4; ++nt) {
            const int h = wn * 64 + nt * 16 + lm;
            const float bh = b1p[h];
            const int hh = h & 63;
#pragma unroll
            for (int r = 0; r < 4; ++r) {
                int i = wm * 32 + mt * 16 + q * 4 + r;
                float val = acc[mt][nt][r] + bh;
                val = val > 0.f ? val : 0.01f * val;
                int addr = i * 64 + (((hh & ~7) ^ ((i & 7) << 3)) | (hh & 7));
                Dsh[wn][addr] = (f16)val;
            }
        }
    stageW(Wt2, 128, 0, 0);
    stageW(Wt2, 128, 64, 1);
    __syncthreads();

    // ---- layer 2 ----
    zero_acc();
    mfma2(Dsh[0], Wsh[0]);
    mfma2(Dsh[1], Wsh[1]);

    // ---- contraction epilogue: out[b,o,d] += sum_i (fk+b2)*x_i/N ----
    float p[4][3];
#pragma unroll
    for (int nt = 0; nt < 4; ++nt)
#pragma unroll
        for (int d = 0; d < 3; ++d) p[nt][d] = 0.f;
    float bo[4];
#pragma unroll
    for (int nt = 0; nt < 4; ++nt) bo[nt] = b2p[wn * 64 + nt * 16 + lm];
#pragma unroll
    for (int mt = 0; mt < 2; ++mt)
#pragma unroll
        for (int r = 0; r < 4; ++r) {
            int i = wm * 32 + mt * 16 + q * 4 + r;
            float x0 = xi[i * 4], x1 = xi[i * 4 + 1], x2 = xi[i * 4 + 2];
#pragma unroll
            for (int nt = 0; nt < 4; ++nt) {
                float fkv = acc[mt][nt][r] + bo[nt];
                p[nt][0] = fmaf(fkv, x0, p[nt][0]);
                p[nt][1] = fmaf(fkv, x1, p[nt][1]);
                p[nt][2] = fmaf(fkv, x2, p[nt][2]);
            }
        }
#pragma unroll
    for (int nt = 0; nt < 4; ++nt)
#pragma unroll
        for (int d = 0; d < 3; ++d) {
            float s = p[nt][d];
            s += __shfl_xor(s, 16);
            s += __shfl_xor(s, 32);
            if (q == 0) {
                int o = wn * 64 + nt * 16 + lm;
                atomicAdd(&outp[(b * 128 + o) * 3 + d], s * (1.0f / 1024.0f));
            }
        }
}

extern "C" void kernel_launch(void* const* d_in, const int* in_sizes, int n_in,
                              void* d_out, int out_size, void* d_ws, size_t ws_size,
                              hipStream_t stream) {
    const float* x  = (const float*)d_in[0];
    const float* u  = (const float*)d_in[1];
    const float* W0 = (const float*)d_in[2];
    const float* b0 = (const float*)d_in[3];
    const float* W1 = (const float*)d_in[4];
    const float* b1 = (const float*)d_in[5];
    const float* W2 = (const float*)d_in[6];
    const float* b2 = (const float*)d_in[7];

    char* ws = (char*)d_ws;
    f16*   Wt0   = (f16*)(ws + WT0_OFF);
    f16*   Wt1   = (f16*)(ws + WT1_OFF);
    f16*   Wt2   = (f16*)(ws + WT2_OFF);
    float* w8v   = (float*)(ws + W8_OFF);
    float* bias0 = (float*)(ws + BIAS0_OFF);
    float* out   = (float*)d_out;

    hipMemsetAsync(d_out, 0, (size_t)out_size * sizeof(float), stream);
    prep_kernel<<<19, 256, 0, stream>>>(u, W0, b0, W1, W2, Wt0, Wt1, Wt2, w8v, bias0);
    fused_kernel<<<512, 256, 0, stream>>>(x, b1, b2, Wt0, Wt1, Wt2, w8v, bias0, out);
}

// Round 4
// 96.445 us; speedup vs baseline: 1.0988x; 1.0414x over previous
//
#include <hip/hip_runtime.h>
#include <hip/hip_fp16.h>

typedef _Float16 f16;
typedef f16 f16x4 __attribute__((ext_vector_type(4)));
typedef f16 f16x8 __attribute__((ext_vector_type(8)));
typedef float f32x4 __attribute__((ext_vector_type(4)));

#define NN 1024

// workspace layout (bytes)
// img: f16 [20][8192] — pre-swizzled LDS images of all B-operand chunks:
//   chunks 0..15 : W0^T 64-j chunks (rows h=0..127, cols j local)
//   chunk 16,17  : W1^T (k=hi 0..63 / 64..127)
//   chunk 18,19  : W2^T (k=h  0..63 / 64..127)
// element (r, col) of a chunk lives at img[c*8192 + r*64 + (col ^ ((r&7)<<3))]
#define IMG_OFF   0
#define W8_OFF    327680                 // f32 [128] : W0[8][:] (norm row)
#define BIAS0_OFF 328192                 // f32 [32][128] : b0 + u[b] @ W0[0:8]

__global__ __launch_bounds__(256) void prep_kernel(
    const float* __restrict__ u,  const float* __restrict__ W0,
    const float* __restrict__ b0, const float* __restrict__ W1,
    const float* __restrict__ W2,
    f16* __restrict__ img, float* __restrict__ w8v, float* __restrict__ bias0,
    float* __restrict__ outp)
{
    const int t = threadIdx.x;
    const int blk = blockIdx.x;
    if (blk < 160) {
        // 160 blocks x 256 threads x 4 f16 = 163840 = 20*8192
        int flat = blk * 1024 + t * 4;
        int c = flat >> 13;
        int rem = flat & 8191;
        int r = rem >> 6;
        int s = rem & 63;                    // swizzled col start (multiple of 4)
        int colb = s ^ ((r & 7) << 3);       // unswizzle (bits 3..5)
        f16x4 v;
#pragma unroll
        for (int e = 0; e < 4; ++e) {
            int col = colb + e;
            float val;
            if (c < 16)       val = W0[(9 + c * 64 + col) * 128 + r];
            else if (c == 16) val = W1[col * 128 + r];
            else if (c == 17) val = W1[(64 + col) * 128 + r];
            else if (c == 18) val = W2[col * 128 + r];
            else              val = W2[(64 + col) * 128 + r];
            v[e] = (f16)val;
        }
        *(f16x4*)&img[flat] = v;
    } else if (blk < 176) {
        // bias0: 16 blocks x 256 = 4096 = 32 b x 128 h
        int idx = (blk - 160) * 256 + t;
        int b = idx >> 7, h = idx & 127;
        float s = b0[h];
#pragma unroll
        for (int g = 0; g < 8; ++g) s += u[b * 8 + g] * W0[g * 128 + h];
        bias0[idx] = s;
    } else if (blk == 176) {
        if (t < 128) w8v[t] = W0[8 * 128 + t];
    } else {
        // zero d_out: 12 blocks x 1024 floats = 12288
        int idx = (blk - 177) * 1024 + t * 4;
        if (idx < 12288) { float4 z = {0.f, 0.f, 0.f, 0.f}; *(float4*)&outp[idx] = z; }
    }
}

__global__ __launch_bounds__(256, 3) void fused_kernel(
    const float* __restrict__ x, const float* __restrict__ b1p,
    const float* __restrict__ b2p, const f16* __restrict__ img,
    const float* __restrict__ w8v, const float* __restrict__ bias0,
    float* __restrict__ outp)
{
    __shared__ __align__(16) f16 Dsh[2][64 * 64];   // 16 KB
    __shared__ __align__(16) f16 Wsh[2][128 * 64];  // 32 KB
    __shared__ __align__(16) float xi[64 * 4];
    __shared__ float normv[64];
    __shared__ float biass[128];
    __shared__ float w8s[128];

    const int t = threadIdx.x;
    const int b = blockIdx.x >> 4;
    const int i0 = (blockIdx.x & 15) * 64;

    if (t < 192) {
        int i = t / 3, d = t - i * 3;
        xi[i * 4 + d] = x[(size_t)(b * NN + i0 + i) * 3 + d];
    }
    if (t < 128) { biass[t] = bias0[b * 128 + t]; w8s[t] = w8v[t]; }
    __syncthreads();
    if (t < 64) {
        float a0 = xi[t * 4], a1 = xi[t * 4 + 1], a2 = xi[t * 4 + 2];
        normv[t] = __builtin_amdgcn_sqrtf(a0 * a0 + a1 * a1 + a2 * a2);
    }

    const int lane = t & 63, wv = t >> 6;
    const int wm = wv >> 1, wn = wv & 1;     // main wave tile: 32 i x 64 h
    const int lm = lane & 15, q = lane >> 4;

    // xi B-fragments for the dot-MFMA: lane(q==0,lm) holds coords of
    // i = it*16+lm in k-slots 0..2 (16x16x16 layout, verified rounds 1/2).
    f16x4 bi[4];
#pragma unroll
    for (int it = 0; it < 4; ++it) {
        f16x4 v; v[0] = (f16)0; v[1] = (f16)0; v[2] = (f16)0; v[3] = (f16)0;
        if (q == 0) {
            int ii = it * 16 + lm;
            v[0] = (f16)xi[ii * 4];
            v[1] = (f16)xi[ii * 4 + 1];
            v[2] = (f16)xi[ii * 4 + 2];
        }
        bi[it] = v;
    }

    // preload ALL xj A-fragments (16 chunks, this wave's 16-j group each)
    f16x4 aj[16];
#pragma unroll
    for (int jc = 0; jc < 16; ++jc) {
        f16x4 a; a[0] = (f16)0; a[1] = (f16)0; a[2] = (f16)0; a[3] = (f16)0;
        if (q == 0) {
            const float* p = x + (size_t)(b * NN + jc * 64 + wv * 16 + lm) * 3;
            a[0] = (f16)p[0]; a[1] = (f16)p[1]; a[2] = (f16)p[2];
        }
        aj[jc] = a;
    }

    f32x4 acc[2][4];
    auto zero_acc = [&]() {
#pragma unroll
        for (int mt = 0; mt < 2; ++mt)
#pragma unroll
            for (int nt = 0; nt < 4; ++nt)
#pragma unroll
                for (int e = 0; e < 4; ++e) acc[mt][nt][e] = 0.f;
    };
    zero_acc();

    // async stage of image chunk c into Wsh[buf] (16 KB, LDS-linear order;
    // per-lane lds addr = wave-uniform base + lane*16B, the glds ordering)
    auto stage = [&](int c, int buf) {
        const f16* g = img + c * 8192;
#pragma unroll
        for (int k = 0; k < 4; ++k) {
            int off = (t + k * 256) * 8;   // f16 units; 16B per thread
            __builtin_amdgcn_global_load_lds(
                (const __attribute__((address_space(1))) unsigned int*)(g + off),
                (__attribute__((address_space(3))) unsigned int*)(&Wsh[buf][off]),
                16, 0, 0);
        }
    };

    // dot-MFMA chunk -> sqrt -> packed b64 stores into Dsh[buf]
    auto dotstore = [&](f16x4 ajf, int buf) {
        f32x4 cg[4];
#pragma unroll
        for (int it = 0; it < 4; ++it) {
            f32x4 z; z[0] = 0.f; z[1] = 0.f; z[2] = 0.f; z[3] = 0.f;
            cg[it] = __builtin_amdgcn_mfma_f32_16x16x16f16(ajf, bi[it], z, 0, 0, 0);
        }
#pragma unroll
        for (int it = 0; it < 4; ++it) {
            f16x4 dv;
#pragma unroll
            for (int r = 0; r < 4; ++r)
                dv[r] = (f16)__builtin_amdgcn_sqrtf(fmaxf(cg[it][r], 0.f));
            int row = it * 16 + lm;            // i
            int colstart = wv * 16 + q * 4;    // j
            int addr = row * 64 + (((colstart & ~7) ^ ((row & 7) << 3)) | (colstart & 7));
            *(f16x4*)&Dsh[buf][addr] = dv;
        }
    };

    auto mfma2 = [&](const f16* Ab, const f16* Bb) {
#pragma unroll
        for (int ks = 0; ks < 2; ++ks) {
            const int col = ks * 32 + q * 8;
            f16x8 af[2], bf[4];
#pragma unroll
            for (int mt = 0; mt < 2; ++mt) {
                int row = wm * 32 + mt * 16 + lm;
                af[mt] = *(const f16x8*)(Ab + row * 64 + (col ^ ((row & 7) << 3)));
            }
#pragma unroll
            for (int nt = 0; nt < 4; ++nt) {
                int row = wn * 64 + nt * 16 + lm;
                bf[nt] = *(const f16x8*)(Bb + row * 64 + (col ^ ((row & 7) << 3)));
            }
#pragma unroll
            for (int mt = 0; mt < 2; ++mt)
#pragma unroll
                for (int nt = 0; nt < 4; ++nt)
                    acc[mt][nt] = __builtin_amdgcn_mfma_f32_16x16x32_f16(
                        af[mt], bf[nt], acc[mt][nt], 0, 0, 0);
        }
    };

    // ---- prologue: chunk 0 ----
    stage(0, 0);
    dotstore(aj[0], 0);
    __syncthreads();

    // ---- layer-0 K-loop: fully unrolled, one barrier per chunk ----
#pragma unroll
    for (int jc = 0; jc < 16; ++jc) {
        const int cur = jc & 1, nxt = cur ^ 1;
        stage(jc + 1, nxt);                 // jc==15: chunk 16 (W1 lo) -> Wsh[0]
        if (jc < 15) dotstore(aj[jc + 1], nxt);
        mfma2(Dsh[cur], Wsh[cur]);
        __syncthreads();
    }
    // PARITY NOTE: at jc==15, nxt==0, so chunk 16 (W1 k=0..63) is in Wsh[0].

    // ---- epilogue 0: h0 = leaky(acc + bias + norm*w8) -> Dsh[wn] ----
    //      Dsh[0] = h0[:, 0:64], Dsh[1] = h0[:, 64:128]
#pragma unroll
    for (int mt = 0; mt < 2; ++mt)
#pragma unroll
        for (int nt = 0; nt < 4; ++nt) {
            const int h = wn * 64 + nt * 16 + lm;
            const float bh = biass[h], w8h = w8s[h];
            const int hh = h & 63;
#pragma unroll
            for (int r = 0; r < 4; ++r) {
                int i = wm * 32 + mt * 16 + q * 4 + r;
                float val = acc[mt][nt][r] + bh + normv[i] * w8h;
                val = val > 0.f ? val : 0.01f * val;
                int addr = i * 64 + (((hh & ~7) ^ ((i & 7) << 3)) | (hh & 7));
                Dsh[wn][addr] = (f16)val;
            }
        }
    stage(17, 1);                           // W1 k=64..127 -> Wsh[1]
    __syncthreads();

    // ---- layer 1 ----
    zero_acc();
    mfma2(Dsh[0], Wsh[0]);   // h0 k 0..63   x  W1 chunk16 (in Wsh[0])
    mfma2(Dsh[1], Wsh[1]);   // h0 k 64..127 x  W1 chunk17 (in Wsh[1])
    __syncthreads();

    // ---- epilogue 1: h1 = leaky(acc + b1) -> Dsh[wn] ----
#pragma unroll
    for (int mt = 0; mt < 2; ++mt)
#pragma unroll
        for (int nt = 0; nt < 4; ++nt) {
            const int h = wn * 64 + nt * 16 + lm;
            const float bh = b1p[h];
            const int hh = h & 63;
#pragma unroll
            for (int r = 0; r < 4; ++r) {
                int i = wm * 32 + mt * 16 + q * 4 + r;
                float val = acc[mt][nt][r] + bh;
                val = val > 0.f ? val : 0.01f * val;
                int addr = i * 64 + (((hh & ~7) ^ ((i & 7) << 3)) | (hh & 7));
                Dsh[wn][addr] = (f16)val;
            }
        }
    stage(18, 0);                           // W2 k=0..63  -> Wsh[0]
    stage(19, 1);                           // W2 k=64..127 -> Wsh[1]
    __syncthreads();

    // ---- layer 2 ----
    zero_acc();
    mfma2(Dsh[0], Wsh[0]);
    mfma2(Dsh[1], Wsh[1]);

    // ---- contraction epilogue: out[b,o,d] += sum_i (fk+b2)*x_i / N ----
    float p[4][3];
#pragma unroll
    for (int nt = 0; nt < 4; ++nt)
#pragma unroll
        for (int d = 0; d < 3; ++d) p[nt][d] = 0.f;
    float bo[4];
#pragma unroll
    for (int nt = 0; nt < 4; ++nt) bo[nt] = b2p[wn * 64 + nt * 16 + lm];
#pragma unroll
    for (int mt = 0; mt < 2; ++mt)
#pragma unroll
        for (int r = 0; r < 4; ++r) {
            int i = wm * 32 + mt * 16 + q * 4 + r;
            float x0 = xi[i * 4], x1 = xi[i * 4 + 1], x2 = xi[i * 4 + 2];
#pragma unroll
            for (int nt = 0; nt < 4; ++nt) {
                float fkv = acc[mt][nt][r] + bo[nt];
                p[nt][0] = fmaf(fkv, x0, p[nt][0]);
                p[nt][1] = fmaf(fkv, x1, p[nt][1]);
                p[nt][2] = fmaf(fkv, x2, p[nt][2]);
            }
        }
#pragma unroll
    for (int nt = 0; nt < 4; ++nt)
#pragma unroll
        for (int d = 0; d < 3; ++d) {
            float s = p[nt][d];
            s += __shfl_xor(s, 16);
            s += __shfl_xor(s, 32);
            if (q == 0) {
                int o = wn * 64 + nt * 16 + lm;
                atomicAdd(&outp[(b * 128 + o) * 3 + d], s * (1.0f / 1024.0f));
            }
        }
}

extern "C" void kernel_launch(void* const* d_in, const int* in_sizes, int n_in,
                              void* d_out, int out_size, void* d_ws, size_t ws_size,
                              hipStream_t stream) {
    const float* x  = (const float*)d_in[0];
    const float* u  = (const float*)d_in[1];
    const float* W0 = (const float*)d_in[2];
    const float* b0 = (const float*)d_in[3];
    const float* W1 = (const float*)d_in[4];
    const float* b1 = (const float*)d_in[5];
    const float* W2 = (const float*)d_in[6];
    const float* b2 = (const float*)d_in[7];

    char* ws = (char*)d_ws;
    f16*   img   = (f16*)(ws + IMG_OFF);
    float* w8v   = (float*)(ws + W8_OFF);
    float* bias0 = (float*)(ws + BIAS0_OFF);
    float* out   = (float*)d_out;

    prep_kernel<<<189, 256, 0, stream>>>(u, W0, b0, W1, W2, img, w8v, bias0, out);
    fused_kernel<<<512, 256, 0, stream>>>(x, b1, b2, img, w8v, bias0, out);
}

// Round 5
// 92.998 us; speedup vs baseline: 1.1395x; 1.0371x over previous
//
#include <hip/hip_runtime.h>
#include <hip/hip_fp16.h>

typedef _Float16 f16;
typedef f16 f16x4 __attribute__((ext_vector_type(4)));
typedef f16 f16x8 __attribute__((ext_vector_type(8)));
typedef float f32x4 __attribute__((ext_vector_type(4)));

#define NN 1024

// workspace layout (bytes)
// img2: f16 [20][8192] — B-operand images in FRAGMENT-LINEAR order:
//   per (chunk c, wn half): 4096 f16 = [nt:4][ks:2][lane:64][8 f16],
//   element = B[n = wn*64+nt*16+lm][k = ks*32+q*8+s], lane = q*16+lm.
//   chunks 0..15 : W0^T j-chunks (B[n=h][k=j_local], j = c*64+k)
//   chunks 16,17 : W1   (B[n=ho][k], hi = (c-16)*64+k)
//   chunks 18,19 : W2   (B[n=o ][k], h  = (c-18)*64+k)
#define IMG2_OFF  0
#define W8_OFF    327680                 // f32 [128] : W0[8][:] (norm row)
#define BIAS0_OFF 328192                 // f32 [32][128] : b0 + u[b] @ W0[0:8]

__global__ __launch_bounds__(256) void prep_kernel(
    const float* __restrict__ u,  const float* __restrict__ W0,
    const float* __restrict__ b0, const float* __restrict__ W1,
    const float* __restrict__ W2,
    f16* __restrict__ img2, float* __restrict__ w8v, float* __restrict__ bias0,
    float* __restrict__ outp)
{
    const int t = threadIdx.x;
    const int blk = blockIdx.x;
    if (blk < 160) {
        // 160 blocks x 256 threads x 4 f16 = 163840 = 20*8192
        int flat = blk * 1024 + t * 4;
        int c   = flat >> 13;
        int rem = flat & 8191;
        int s0  = rem & 7;              // 0 or 4
        int lm  = (rem >> 3) & 15;
        int q   = (rem >> 7) & 3;
        int ks  = (rem >> 9) & 1;
        int nt  = (rem >> 10) & 3;
        int wn  = (rem >> 12) & 1;
        int n = wn * 64 + nt * 16 + lm;
        f16x4 v;
#pragma unroll
        for (int e = 0; e < 4; ++e) {
            int k = ks * 32 + q * 8 + s0 + e;
            float val;
            if (c < 16)       val = W0[(9 + c * 64 + k) * 128 + n];
            else if (c < 18)  val = W1[((c - 16) * 64 + k) * 128 + n];
            else              val = W2[((c - 18) * 64 + k) * 128 + n];
            v[e] = (f16)val;
        }
        *(f16x4*)&img2[flat] = v;
    } else if (blk < 176) {
        // bias0: 16 blocks x 256 = 4096 = 32 b x 128 h
        int idx = (blk - 160) * 256 + t;
        int b = idx >> 7, h = idx & 127;
        float s = b0[h];
#pragma unroll
        for (int g = 0; g < 8; ++g) s += u[b * 8 + g] * W0[g * 128 + h];
        bias0[idx] = s;
    } else if (blk == 176) {
        if (t < 128) w8v[t] = W0[8 * 128 + t];
    } else {
        // zero d_out: 12 blocks x 1024 floats = 12288
        int idx = (blk - 177) * 1024 + t * 4;
        if (idx < 12288) { float4 z = {0.f, 0.f, 0.f, 0.f}; *(float4*)&outp[idx] = z; }
    }
}

__global__ __launch_bounds__(256, 4) void fused_kernel(
    const float* __restrict__ x, const float* __restrict__ b1p,
    const float* __restrict__ b2p, const f16* __restrict__ img2,
    const float* __restrict__ w8v, const float* __restrict__ bias0,
    float* __restrict__ outp)
{
    // ~26 KB LDS -> 4 blocks/CU
    __shared__ __align__(16) f16 Dsh[2][64 * 64];   // 16 KB (XOR-swizzled)
    __shared__ __align__(16) f16 xjsh[1024 * 4];    // 8 KB: all x rows, f16, [3]=0
    __shared__ __align__(16) float xi[64 * 4];
    __shared__ float normv[64];
    __shared__ float biass[128];
    __shared__ float w8s[128];

    const int t = threadIdx.x;
    const int b = blockIdx.x >> 4;
    const int i0 = (blockIdx.x & 15) * 64;

    // stage all 1024 x-rows as f16x4 (w=0): 3 float4 loads / thread
    {
        const float* xb = x + (size_t)b * NN * 3;
        float4 v0 = *(const float4*)(xb + t * 12);
        float4 v1 = *(const float4*)(xb + t * 12 + 4);
        float4 v2 = *(const float4*)(xb + t * 12 + 8);
        f16x4 r0; r0[0] = (f16)v0.x; r0[1] = (f16)v0.y; r0[2] = (f16)v0.z; r0[3] = (f16)0;
        f16x4 r1; r1[0] = (f16)v0.w; r1[1] = (f16)v1.x; r1[2] = (f16)v1.y; r1[3] = (f16)0;
        f16x4 r2; r2[0] = (f16)v1.z; r2[1] = (f16)v1.w; r2[2] = (f16)v2.x; r2[3] = (f16)0;
        f16x4 r3; r3[0] = (f16)v2.y; r3[1] = (f16)v2.z; r3[2] = (f16)v2.w; r3[3] = (f16)0;
        *(f16x4*)&xjsh[(t * 4 + 0) * 4] = r0;
        *(f16x4*)&xjsh[(t * 4 + 1) * 4] = r1;
        *(f16x4*)&xjsh[(t * 4 + 2) * 4] = r2;
        *(f16x4*)&xjsh[(t * 4 + 3) * 4] = r3;
    }
    if (t < 192) {
        int i = t / 3, d = t - i * 3;
        xi[i * 4 + d] = x[(size_t)(b * NN + i0 + i) * 3 + d];
    }
    if (t < 128) { biass[t] = bias0[b * 128 + t]; w8s[t] = w8v[t]; }
    __syncthreads();
    if (t < 64) {
        float a0 = xi[t * 4], a1 = xi[t * 4 + 1], a2 = xi[t * 4 + 2];
        normv[t] = __builtin_amdgcn_sqrtf(a0 * a0 + a1 * a1 + a2 * a2);
    }

    const int lane = t & 63, wv = t >> 6;
    const int wm = wv >> 1, wn = wv & 1;     // main wave tile: 32 i x 64 h
    const int lm = lane & 15, q = lane >> 4;

    // xi B-fragments for dot-MFMA (16x16x16): lane(q==0,lm) holds coords of
    // i = it*16+lm in k-slots 0..2.
    f16x4 bi[4];
#pragma unroll
    for (int it = 0; it < 4; ++it) {
        f16x4 v; v[0] = (f16)0; v[1] = (f16)0; v[2] = (f16)0; v[3] = (f16)0;
        if (q == 0) {
            int ii = it * 16 + lm;
            v[0] = (f16)xi[ii * 4];
            v[1] = (f16)xi[ii * 4 + 1];
            v[2] = (f16)xi[ii * 4 + 2];
        }
        bi[it] = v;
    }

    f32x4 acc[2][4];
    auto zero_acc = [&]() {
#pragma unroll
        for (int mt = 0; mt < 2; ++mt)
#pragma unroll
            for (int nt = 0; nt < 4; ++nt)
#pragma unroll
                for (int e = 0; e < 4; ++e) acc[mt][nt][e] = 0.f;
    };
    zero_acc();

    // dot-MFMA chunk jc -> sqrt -> packed b64 stores into Dsh[buf]
    auto dotstore = [&](int jc, int buf) {
        f16x4 ajv; ajv[0] = (f16)0; ajv[1] = (f16)0; ajv[2] = (f16)0; ajv[3] = (f16)0;
        if (q == 0)
            ajv = *(const f16x4*)&xjsh[(jc * 64 + wv * 16 + lm) * 4];
        f32x4 cg[4];
#pragma unroll
        for (int it = 0; it < 4; ++it) {
            f32x4 z; z[0] = 0.f; z[1] = 0.f; z[2] = 0.f; z[3] = 0.f;
            cg[it] = __builtin_amdgcn_mfma_f32_16x16x16f16(ajv, bi[it], z, 0, 0, 0);
        }
#pragma unroll
        for (int it = 0; it < 4; ++it) {
            f16x4 dv;
#pragma unroll
            for (int r = 0; r < 4; ++r)
                dv[r] = (f16)__builtin_amdgcn_sqrtf(fmaxf(cg[it][r], 0.f));
            int row = it * 16 + lm;            // i
            int colstart = wv * 16 + q * 4;    // j (k-dim of main GEMM)
            int addr = row * 64 + (((colstart & ~7) ^ ((row & 7) << 3)) | (colstart & 7));
            *(f16x4*)&Dsh[buf][addr] = dv;
        }
    };

    // one K=64 step: A from Dsh[dbuf], B fragments DIRECT from L2 (img2 chunk c);
    // optionally generate next D chunk between issue and use.
    auto kstep = [&](int dbuf, int c, int dotjc, int dotbuf) {
        f16x8 af[2][2];
#pragma unroll
        for (int mt = 0; mt < 2; ++mt)
#pragma unroll
            for (int ks = 0; ks < 2; ++ks) {
                int row = wm * 32 + mt * 16 + lm;
                int col = ks * 32 + q * 8;
                af[mt][ks] = *(const f16x8*)(Dsh[dbuf] + row * 64 + (col ^ ((row & 7) << 3)));
            }
        const f16* wb = img2 + (size_t)(c * 2 + wn) * 4096 + lane * 8;
        f16x8 bf[4][2];
#pragma unroll
        for (int nt = 0; nt < 4; ++nt)
#pragma unroll
            for (int ks = 0; ks < 2; ++ks)
                bf[nt][ks] = *(const f16x8*)(wb + (nt * 2 + ks) * 512);
        if (dotjc >= 0) dotstore(dotjc, dotbuf);
#pragma unroll
        for (int ks = 0; ks < 2; ++ks)
#pragma unroll
            for (int mt = 0; mt < 2; ++mt)
#pragma unroll
                for (int nt = 0; nt < 4; ++nt)
                    acc[mt][nt] = __builtin_amdgcn_mfma_f32_16x16x32_f16(
                        af[mt][ks], bf[nt][ks], acc[mt][nt], 0, 0, 0);
    };

    // ---- prologue: D chunk 0 ----
    dotstore(0, 0);
    __syncthreads();

    // ---- layer-0 K-loop: one barrier per chunk, W never touches LDS ----
#pragma unroll
    for (int jc = 0; jc < 16; ++jc) {
        const int cur = jc & 1, nxt = cur ^ 1;
        kstep(cur, jc, (jc < 15) ? jc + 1 : -1, nxt);
        __syncthreads();
    }

    // ---- epilogue 0: h0 = leaky(acc + bias + norm*w8) -> Dsh[wn] ----
    //      Dsh[0] = h0[:, 0:64], Dsh[1] = h0[:, 64:128]
#pragma unroll
    for (int mt = 0; mt < 2; ++mt)
#pragma unroll
        for (int nt = 0; nt < 4; ++nt) {
            const int h = wn * 64 + nt * 16 + lm;
            const float bh = biass[h], w8h = w8s[h];
            const int hh = h & 63;
#pragma unroll
            for (int r = 0; r < 4; ++r) {
                int i = wm * 32 + mt * 16 + q * 4 + r;
                float val = acc[mt][nt][r] + bh + normv[i] * w8h;
                val = val > 0.f ? val : 0.01f * val;
                int addr = i * 64 + (((hh & ~7) ^ ((i & 7) << 3)) | (hh & 7));
                Dsh[wn][addr] = (f16)val;
            }
        }
    __syncthreads();

    // ---- layer 1: B = chunks 16,17 ----
    zero_acc();
    kstep(0, 16, -1, 0);
    kstep(1, 17, -1, 0);
    __syncthreads();

    // ---- epilogue 1: h1 = leaky(acc + b1) -> Dsh[wn] ----
#pragma unroll
    for (int mt = 0; mt < 2; ++mt)
#pragma unroll
        for (int nt = 0; nt < 4; ++nt) {
            const int h = wn * 64 + nt * 16 + lm;
            const float bh = b1p[h];
            const int hh = h & 63;
#pragma unroll
            for (int r = 0; r < 4; ++r) {
                int i = wm * 32 + mt * 16 + q * 4 + r;
                float val = acc[mt][nt][r] + bh;
                val = val > 0.f ? val : 0.01f * val;
                int addr = i * 64 + (((hh & ~7) ^ ((i & 7) << 3)) | (hh & 7));
                Dsh[wn][addr] = (f16)val;
            }
        }
    __syncthreads();

    // ---- layer 2: B = chunks 18,19 ----
    zero_acc();
    kstep(0, 18, -1, 0);
    kstep(1, 19, -1, 0);

    // ---- contraction epilogue: out[b,o,d] += sum_i (fk+b2)*x_i / N ----
    float p[4][3];
#pragma unroll
    for (int nt = 0; nt < 4; ++nt)
#pragma unroll
        for (int d = 0; d < 3; ++d) p[nt][d] = 0.f;
    float bo[4];
#pragma unroll
    for (int nt = 0; nt < 4; ++nt) bo[nt] = b2p[wn * 64 + nt * 16 + lm];
#pragma unroll
    for (int mt = 0; mt < 2; ++mt)
#pragma unroll
        for (int r = 0; r < 4; ++r) {
            int i = wm * 32 + mt * 16 + q * 4 + r;
            float x0 = xi[i * 4], x1 = xi[i * 4 + 1], x2 = xi[i * 4 + 2];
#pragma unroll
            for (int nt = 0; nt < 4; ++nt) {
                float fkv = acc[mt][nt][r] + bo[nt];
                p[nt][0] = fmaf(fkv, x0, p[nt][0]);
                p[nt][1] = fmaf(fkv, x1, p[nt][1]);
                p[nt][2] = fmaf(fkv, x2, p[nt][2]);
            }
        }
#pragma unroll
    for (int nt = 0; nt < 4; ++nt)
#pragma unroll
        for (int d = 0; d < 3; ++d) {
            float s = p[nt][d];
            s += __shfl_xor(s, 16);
            s += __shfl_xor(s, 32);
            if (q == 0) {
                int o = wn * 64 + nt * 16 + lm;
                atomicAdd(&outp[(b * 128 + o) * 3 + d], s * (1.0f / 1024.0f));
            }
        }
}

extern "C" void kernel_launch(void* const* d_in, const int* in_sizes, int n_in,
                              void* d_out, int out_size, void* d_ws, size_t ws_size,
                              hipStream_t stream) {
    const float* x  = (const float*)d_in[0];
    const float* u  = (const float*)d_in[1];
    const float* W0 = (const float*)d_in[2];
    const float* b0 = (const float*)d_in[3];
    const float* W1 = (const float*)d_in[4];
    const float* b1 = (const float*)d_in[5];
    const float* W2 = (const float*)d_in[6];
    const float* b2 = (const float*)d_in[7];

    char* ws = (char*)d_ws;
    f16*   img2  = (f16*)(ws + IMG2_OFF);
    float* w8v   = (float*)(ws + W8_OFF);
    float* bias0 = (float*)(ws + BIAS0_OFF);
    float* out   = (float*)d_out;

    prep_kernel<<<189, 256, 0, stream>>>(u, W0, b0, W1, W2, img2, w8v, bias0, out);
    fused_kernel<<<512, 256, 0, stream>>>(x, b1, b2, img2, w8v, bias0, out);
}